// Round 8
// baseline (157.874 us; speedup 1.0000x reference)
//
#include <hip/hip_runtime.h>
#include <math.h>

// CriticGraphPolicy, MI355X (gfx950). Round 8: SPLIT kernels.
// R1-R7 monolith was latency-bound at 2 waves/SIMD (occupancy pinned by the
// union of phase-0 and k-loop LDS+register footprints). Split:
//   pack_weights -> img (bf16 tiles, d_ws)
//   phase0_kernel -> xum bf16[B][64] (d_ws), 16+ waves/CU
//   mlp_kernel: 1024 thr / 16 waves / acc2[2][5]=40 AGPR -> ~100 regs
//               -> 4 waves/SIMD, counted-vmcnt depth-2 tile pipeline.

#define BTOT   65536
#define TILE_B 23808             // packed weight tile: w2 19200 + w1 4608
#define TILE_U 11904
#define W2_B   19200
#define NTILE  26                // 2 q-nets x 13 k-tiles
#define XUM_OFF 655360ull        // byte offset of xum image in d_ws (img = 619,008 B)

// phase0
#define PH_THR  512
#define PH_ROWS 128
#define PH_BLK  (BTOT / PH_ROWS) // 512
#define F1W 0
#define F1B 2112
#define F2W 2176
#define F2B 6272
#define F3W 6336
#define F3B 8384
#define W0_FLOATS 8416           // 33,664 B

// mlp
#define ML_THR  1024
#define ML_ROWS 128
#define ML_BLK  (BTOT / ML_ROWS) // 512

typedef float  f32x4 __attribute__((ext_vector_type(4)));
typedef __bf16 bf16x8 __attribute__((ext_vector_type(8)));
typedef unsigned short u16x8 __attribute__((ext_vector_type(8)));

__device__ __forceinline__ unsigned short f2b(float f) {
  union { float f; unsigned int u; } v; v.f = f;
  return (unsigned short)((v.u + 0x7fffu + ((v.u >> 16) & 1u)) >> 16);
}
__device__ __forceinline__ float b2f(unsigned short u) {
  union { unsigned int u; float f; } v; v.u = ((unsigned int)u) << 16;
  return v.f;
}
__device__ __forceinline__ f32x4 MFMA(bf16x8 a, bf16x8 b, f32x4 c) {
  return __builtin_amdgcn_mfma_f32_16x16x32_bf16(a, b, c, 0, 0, 0);
}
__device__ __forceinline__ bf16x8 ld8(const unsigned short* p) {   // LDS or global
  return __builtin_bit_cast(bf16x8, *(const u16x8*)p);
}
__device__ __forceinline__ void gl_lds16(const void* g, void* l) {
  __builtin_amdgcn_global_load_lds(
      (__attribute__((address_space(1))) void*)(unsigned long long)(const char*)g,
      (__attribute__((address_space(3))) void*)(unsigned long long)(char*)l,
      16, 0, 0);
}
__device__ __forceinline__ void gl_lds4(const void* g, void* l) {
  __builtin_amdgcn_global_load_lds(
      (__attribute__((address_space(1))) void*)(unsigned long long)(const char*)g,
      (__attribute__((address_space(3))) void*)(unsigned long long)(char*)l,
      4, 0, 0);
}
__device__ __forceinline__ float ftanh(float x) {
  float e = __builtin_amdgcn_exp2f(x * 2.885390081777927f);
  return (e - 1.0f) * __builtin_amdgcn_rcpf(e + 1.0f);
}

// ---------------- weight pack kernel (layout unchanged from R5) ----------------
struct PackP { const float* qp[12]; unsigned short* ws; };

__global__ void pack_weights(PackP P) {
  const int b = blockIdx.x, tid = threadIdx.x;
  if (b < 61) {                       // w2: 26 tiles * 4 kc * 300 col
    int idx = b * 512 + tid;
    if (idx >= 31200) return;
    int col = idx % 300; int r = idx / 300;
    int kc = r & 3, tile = r >> 2;
    int q = tile / 13, kt = tile % 13;
    const float* w2 = P.qp[q * 6 + 2];
    unsigned short vals[8];
    #pragma unroll
    for (int koff = 0; koff < 8; ++koff) {
      int kg = kt * 32 + kc * 8 + koff;
      float v = (kg < 400) ? w2[kg * 300 + col] : 0.f;
      vals[koff] = f2b(v);
    }
    *(u16x8*)(P.ws + (size_t)tile * TILE_U + (size_t)(kc * 300 + col) * 8) = *(const u16x8*)vals;
  } else {                            // w1eff: 26 tiles * 2304 u16
    int idx = (b - 61) * 512 + tid;
    if (idx >= 59904) return;
    int e = idx % 2304, tile = idx / 2304;
    int q = tile / 13, kt = tile % 13;
    int col = e / 72, k = e % 72;
    int cg = kt * 32 + col;
    unsigned short v = 0;
    if (cg < 400) {
      if (k < 39) v = f2b(P.qp[q * 6 + 0][(6 + k) * 400 + cg]);
      else if (k == 39) v = f2b(P.qp[q * 6 + 1][cg]);
    }
    P.ws[(size_t)tile * TILE_U + 9600 + e] = v;
  }
}

// ---------------- phase-0 kernel: feature MLP -> xum bf16[B][64] ----------------
struct P0 {
  const float* state; const float* action;
  const float* f1w; const float* f1b;
  const float* f2w; const float* f2b;
  const float* f3w; const float* f3b;
  unsigned short* xum;
};

__global__ __launch_bounds__(PH_THR, 4) void phase0_kernel(P0 P) {
  __shared__ float w0[W0_FLOATS];                  // 33,664 B
  __shared__ unsigned short hx[PH_ROWS * 68];      // 17,408 B
  const int tid = threadIdx.x;
  const int row = tid >> 2, sub = tid & 3, j0 = sub * 16;
  const long grow = (long)blockIdx.x * PH_ROWS + row;

  // stage phase-0 weights once per block
  for (int i = tid; i < 528;  i += PH_THR) *(f32x4*)(w0 + F1W + 4*i) = *(const f32x4*)(P.f1w + 4*i);
  for (int i = tid; i < 16;   i += PH_THR) *(f32x4*)(w0 + F1B + 4*i) = *(const f32x4*)(P.f1b + 4*i);
  for (int i = tid; i < 1024; i += PH_THR) *(f32x4*)(w0 + F2W + 4*i) = *(const f32x4*)(P.f2w + 4*i);
  for (int i = tid; i < 16;   i += PH_THR) *(f32x4*)(w0 + F2B + 4*i) = *(const f32x4*)(P.f2b + 4*i);
  for (int i = tid; i < 512;  i += PH_THR) *(f32x4*)(w0 + F3W + 4*i) = *(const f32x4*)(P.f3w + 4*i);
  for (int i = tid; i < 8;    i += PH_THR) *(f32x4*)(w0 + F3B + 4*i) = *(const f32x4*)(P.f3b + 4*i);

  float sa[33];
  {
    const float4* sp = (const float4*)(P.state + grow * 32);
    #pragma unroll
    for (int c = 0; c < 8; ++c) {
      float4 v = sp[c];
      sa[c*4+0] = v.x; sa[c*4+1] = v.y; sa[c*4+2] = v.z; sa[c*4+3] = v.w;
    }
    sa[32] = P.action[grow];
  }
  __syncthreads();

  float acc[16];
  // fc1: h = tanh(l2norm(sa @ w1 + b1))
  #pragma unroll
  for (int j = 0; j < 16; ++j) acc[j] = w0[F1B + j0 + j];
  #pragma unroll 4
  for (int i = 0; i < 33; ++i) {
    const float s = sa[i];
    const f32x4* wr = (const f32x4*)&w0[F1W + i * 64 + j0];
    #pragma unroll
    for (int c = 0; c < 4; ++c) {
      f32x4 wv = wr[c];
      acc[c*4+0] += s * wv[0]; acc[c*4+1] += s * wv[1];
      acc[c*4+2] += s * wv[2]; acc[c*4+3] += s * wv[3];
    }
  }
  {
    float ss = 0.f;
    #pragma unroll
    for (int j = 0; j < 16; ++j) ss += acc[j] * acc[j];
    ss += __shfl_xor(ss, 1, 64); ss += __shfl_xor(ss, 2, 64);
    const float sc = 1.f / fmaxf(sqrtf(ss), 1e-12f);
    #pragma unroll
    for (int j = 0; j < 16; ++j) hx[row * 68 + j0 + j] = f2b(ftanh(acc[j] * sc));
  }
  __syncthreads();
  // fc2: h2 = tanh(h @ w2[0:64] + b2)
  #pragma unroll
  for (int j = 0; j < 16; ++j) acc[j] = w0[F2B + j0 + j];
  #pragma unroll 4
  for (int i = 0; i < 64; ++i) {
    const float hv = b2f(hx[row * 68 + i]);
    const f32x4* wr = (const f32x4*)&w0[F2W + i * 64 + j0];
    #pragma unroll
    for (int c = 0; c < 4; ++c) {
      f32x4 wv = wr[c];
      acc[c*4+0] += hv * wv[0]; acc[c*4+1] += hv * wv[1];
      acc[c*4+2] += hv * wv[2]; acc[c*4+3] += hv * wv[3];
    }
  }
  __syncthreads();
  #pragma unroll
  for (int j = 0; j < 16; ++j) hx[row * 68 + j0 + j] = f2b(ftanh(acc[j]));
  __syncthreads();
  // fc3: msg = l2norm(h2 @ w3 + b3)
  const int j0m = sub * 8;
  float am[8];
  #pragma unroll
  for (int j = 0; j < 8; ++j) am[j] = w0[F3B + j0m + j];
  #pragma unroll 4
  for (int i = 0; i < 64; ++i) {
    const float hv = b2f(hx[row * 68 + i]);
    const f32x4* wr = (const f32x4*)&w0[F3W + i * 32 + j0m];
    #pragma unroll
    for (int c = 0; c < 2; ++c) {
      f32x4 wv = wr[c];
      am[c*4+0] += hv * wv[0]; am[c*4+1] += hv * wv[1];
      am[c*4+2] += hv * wv[2]; am[c*4+3] += hv * wv[3];
    }
  }
  float sm = 0.f;
  #pragma unroll
  for (int j = 0; j < 8; ++j) sm += am[j] * am[j];
  sm += __shfl_xor(sm, 1, 64); sm += __shfl_xor(sm, 2, 64);
  const float scm = 1.f / fmaxf(sqrtf(sm), 1e-12f);
  __syncthreads();                    // all h2 reads done
  // publish msg to hx[row][0..31]
  #pragma unroll
  for (int j = 0; j < 8; ++j) hx[row * 68 + j0m + j] = f2b(am[j] * scm);
  __syncthreads();
  // assemble xum row: [pos,pos,msg(32),action,1, 0...0] and store 16 cols/thread
  {
    u16x8 v0, v1;
    #pragma unroll
    for (int t = 0; t < 16; ++t) {
      const int c = j0 + t;
      unsigned short u;
      if      (c < 3)  u = f2b(sa[c]);
      else if (c < 6)  u = f2b(sa[c - 3]);
      else if (c < 38) u = hx[row * 68 + (c - 6)];
      else if (c == 38) u = f2b(sa[32]);
      else if (c == 39) u = 0x3f80;
      else              u = 0;
      if (t < 8) v0[t] = u; else v1[t - 8] = u;
    }
    unsigned short* dst = P.xum + (size_t)grow * 64 + j0;
    *(u16x8*)dst = v0;
    *(u16x8*)(dst + 8) = v1;
  }
}

// ---------------- mlp kernel: q1/q2 MLPs via MFMA tile pipeline ----------------
struct P1 {
  const unsigned char* img; const unsigned short* xum;
  const float* q1b2; const float* q1w3; const float* q1b3;
  const float* q2b2; const float* q2w3; const float* q2b3;
  float* out;
};

// stage one 23,808-B tile with 16 waves: wave w: granule w; waves 0-6: granule
// 16+w; wave 7: 256-B tail. vmem ops: w<8 -> 2, w>=8 -> 1.
__device__ __forceinline__ void stage16(const unsigned char* img, int tile,
                                        unsigned char* dst, int w, int lane) {
  const unsigned char* src = img + (size_t)tile * TILE_B;
  gl_lds16(src + (w << 10) + lane * 16, dst + (w << 10));
  if (w < 7)       gl_lds16(src + ((16 + w) << 10) + lane * 16, dst + ((16 + w) << 10));
  else if (w == 7) gl_lds4 (src + 23552 + lane * 4,             dst + 23552);
}

__global__ __launch_bounds__(ML_THR) void mlp_kernel(P1 P) {
  // LDS 80,640 B: bufs 3x23,808 = 71,424 ; h1t [128][36] u16 = 9,216 (xred aliases)
  __shared__ __align__(16) unsigned char smem[80640];
  unsigned char*  bufs = smem;
  unsigned short* h1t  = (unsigned short*)(smem + 71424);
  float*          xred = (float*)(smem + 71424);

  const int tid  = threadIdx.x;
  const int lane = tid & 63, w = tid >> 6;      // 16 waves
  const int rl = lane & 15, g = lane >> 4;

  stage16(P.img, 0, bufs, w, lane);
  stage16(P.img, 1, bufs + TILE_B, w, lane);

  // layer-1 A-fragments from global xum (waves 0-7 own rows w*16..w*16+15)
  bf16x8 af0 = {}, af1 = {};
  if (w < 8) {
    const unsigned short* xr = P.xum + ((size_t)blockIdx.x * ML_ROWS + w * 16 + rl) * 64;
    af0 = ld8(xr + g * 8);
    af1 = ld8(xr + 32 + g * 8);
  }
  asm volatile("s_waitcnt vmcnt(0) lgkmcnt(0)" ::: "memory");
  __builtin_amdgcn_s_barrier();                 // tiles 0,1 resident; af held

  const int wm = w >> 2, wn = w & 3;            // 4 x 32-row bands, 4 x 80-col quarters
  f32x4 acc2[2][5];

  for (int tt = 0; tt < NTILE; ++tt) {
    const int kt = (tt < 13) ? tt : tt - 13;
    const int qx = (tt < 13) ? 0 : 1;
    unsigned char* bufc = bufs + (tt % 3) * TILE_B;
    if (kt == 0) {
      #pragma unroll
      for (int mt = 0; mt < 2; ++mt)
        #pragma unroll
        for (int jn = 0; jn < 5; ++jn) acc2[mt][jn] = (f32x4){0.f, 0.f, 0.f, 0.f};
    }
    if (tt + 2 < NTILE)
      stage16(P.img, tt + 2, bufs + ((tt + 2) % 3) * TILE_B, w, lane);

    // layer1 (waves 0-7): 16 rows x 32 cols of this tile's k-slice
    if (w < 8) {
      const unsigned short* w1c = (const unsigned short*)(bufc + W2_B);
      #pragma unroll
      for (int nt = 0; nt < 2; ++nt) {
        f32x4 a1 = (f32x4){0.f, 0.f, 0.f, 0.f};
        a1 = MFMA(af0, ld8(&w1c[(nt * 16 + rl) * 72 + g * 8]), a1);
        a1 = MFMA(af1, ld8(&w1c[(nt * 16 + rl) * 72 + 32 + g * 8]), a1);
        #pragma unroll
        for (int i = 0; i < 4; ++i)
          h1t[(w * 16 + g * 4 + i) * 36 + nt * 16 + rl] = f2b(fmaxf(a1[i], 0.f));
      }
    }
    asm volatile("s_waitcnt lgkmcnt(0)" ::: "memory");
    __builtin_amdgcn_s_barrier();               // h1t ready; prefetch in flight

    // layer2: wave (wm,wn): rows wm*32..+31 x cols wn*80..+79
    const unsigned short* w2l = (const unsigned short*)bufc;
    bf16x8 bff[5];
    #pragma unroll
    for (int jn = 0; jn < 5; ++jn)
      bff[jn] = ld8(&w2l[g * 2400 + (wn * 80 + jn * 16 + rl) * 8]);
    #pragma unroll
    for (int mt = 0; mt < 2; ++mt) {
      bf16x8 a2f = ld8(&h1t[(wm * 32 + mt * 16 + rl) * 36 + g * 8]);
      #pragma unroll
      for (int jn = 0; jn < 5; ++jn)
        acc2[mt][jn] = MFMA(a2f, bff[jn], acc2[mt][jn]);
    }

    if (kt == 12) {                             // epilogue per q-net
      __syncthreads();                          // all h1t reads done (xred aliases)
      const float* b2p = qx ? P.q2b2 : P.q1b2;
      const float* w3  = qx ? P.q2w3 : P.q1w3;
      const float* b3  = qx ? P.q2b3 : P.q1b3;
      float xp[2][4];
      #pragma unroll
      for (int mt = 0; mt < 2; ++mt)
        #pragma unroll
        for (int i = 0; i < 4; ++i) xp[mt][i] = 0.f;
      #pragma unroll
      for (int jn = 0; jn < 5; ++jn) {
        int n = wn * 80 + jn * 16 + rl;
        if (n < 300) {
          float bv = b2p[n], wv = w3[n];
          #pragma unroll
          for (int mt = 0; mt < 2; ++mt)
            #pragma unroll
            for (int i = 0; i < 4; ++i)
              xp[mt][i] += fmaxf(acc2[mt][jn][i] + bv, 0.f) * wv;
        }
      }
      #pragma unroll
      for (int off = 1; off < 16; off <<= 1)
        #pragma unroll
        for (int mt = 0; mt < 2; ++mt)
          #pragma unroll
          for (int i = 0; i < 4; ++i)
            xp[mt][i] += __shfl_xor(xp[mt][i], off, 64);
      if (rl == 0) {
        #pragma unroll
        for (int mt = 0; mt < 2; ++mt)
          #pragma unroll
          for (int i = 0; i < 4; ++i)
            xred[(wm * 32 + mt * 16 + g * 4 + i) * 4 + wn] = xp[mt][i];
      }
      __syncthreads();
      if (tid < ML_ROWS) {
        const float4 xv = *(const float4*)&xred[tid * 4];
        P.out[(size_t)qx * BTOT + (size_t)blockIdx.x * ML_ROWS + tid] =
            xv.x + xv.y + xv.z + xv.w + b3[0];
      }
    }
    // end of iter: confirm tile tt+1 resident; tile tt+2 stays in flight
    if (tt < NTILE - 1) {
      if (tt == NTILE - 2) { asm volatile("s_waitcnt vmcnt(0)" ::: "memory"); }
      else if (w < 8)      { asm volatile("s_waitcnt vmcnt(2)" ::: "memory"); }
      else                 { asm volatile("s_waitcnt vmcnt(1)" ::: "memory"); }
      __builtin_amdgcn_s_barrier();
    }
  }
}

extern "C" void kernel_launch(void* const* d_in, const int* in_sizes, int n_in,
                              void* d_out, int out_size, void* d_ws, size_t ws_size,
                              hipStream_t stream) {
  (void)in_sizes; (void)n_in; (void)out_size; (void)ws_size;
  PackP K;
  for (int i = 0; i < 12; ++i) K.qp[i] = (const float*)d_in[10 + i];
  K.ws = (unsigned short*)d_ws;
  pack_weights<<<dim3(178), dim3(512), 0, stream>>>(K);

  P0 A;
  A.state  = (const float*)d_in[0];
  A.action = (const float*)d_in[1];
  A.f1w = (const float*)d_in[2]; A.f1b = (const float*)d_in[3];
  A.f2w = (const float*)d_in[4]; A.f2b = (const float*)d_in[5];
  A.f3w = (const float*)d_in[6]; A.f3b = (const float*)d_in[7];
  A.xum = (unsigned short*)((unsigned char*)d_ws + XUM_OFF);
  phase0_kernel<<<dim3(PH_BLK), dim3(PH_THR), 0, stream>>>(A);

  P1 B;
  B.img  = (const unsigned char*)d_ws;
  B.xum  = (const unsigned short*)((unsigned char*)d_ws + XUM_OFF);
  B.q1b2 = (const float*)d_in[13]; B.q1w3 = (const float*)d_in[14]; B.q1b3 = (const float*)d_in[15];
  B.q2b2 = (const float*)d_in[19]; B.q2w3 = (const float*)d_in[20]; B.q2b3 = (const float*)d_in[21];
  B.out  = (float*)d_out;
  mlp_kernel<<<dim3(ML_BLK), dim3(ML_THR), 0, stream>>>(B);
}

// Round 9
// 113.467 us; speedup vs baseline: 1.3914x; 1.3914x over previous
//
#include <hip/hip_runtime.h>
#include <math.h>

// CriticGraphPolicy, MI355X (gfx950). Round 9.
// R8 post-mortem: the 2-phase barrier-locked k-loop (stage->barrier->mfma->
// barrier x26) is the invariant ~125us serializer (m233-style structural
// overhead), not registers/occupancy/DMA depth. R9 deletes it:
//   - weights pre-packed as MFMA-fragment-ordered 1KB blocks (pack_weights)
//   - mlp k-loop reads B-fragments straight from L2 into registers
//     (no LDS weight staging, NO barriers in the k-loop)
//   - only h1 [128][440] bf16 in LDS (440: 2-way-conflict-free, 16B rows)
//   - 6 barriers per block total (vs ~54)
// phase0_kernel unchanged from R8.

#define BTOT   65536
#define XUM_OFF 655360ull        // xum image offset in d_ws (pack img = 638,976 B)

// phase0
#define PH_THR  512
#define PH_ROWS 128
#define PH_BLK  (BTOT / PH_ROWS)
#define F1W 0
#define F1B 2112
#define F2W 2176
#define F2B 6272
#define F3W 6336
#define F3B 8384
#define W0_FLOATS 8416

// mlp
#define ML_THR  1024
#define ML_ROWS 128
#define ML_BLK  (BTOT / ML_ROWS) // 512
#define H1S     440              // h1 col stride (bf16): 880B rows, 16B-aligned, 2-way banks

typedef float  f32x4 __attribute__((ext_vector_type(4)));
typedef __bf16 bf16x8 __attribute__((ext_vector_type(8)));
typedef unsigned short u16x8 __attribute__((ext_vector_type(8)));

__device__ __forceinline__ unsigned short f2b(float f) {
  union { float f; unsigned int u; } v; v.f = f;
  return (unsigned short)((v.u + 0x7fffu + ((v.u >> 16) & 1u)) >> 16);
}
__device__ __forceinline__ float b2f(unsigned short u) {
  union { unsigned int u; float f; } v; v.u = ((unsigned int)u) << 16;
  return v.f;
}
__device__ __forceinline__ f32x4 MFMA(bf16x8 a, bf16x8 b, f32x4 c) {
  return __builtin_amdgcn_mfma_f32_16x16x32_bf16(a, b, c, 0, 0, 0);
}
__device__ __forceinline__ bf16x8 ld8(const unsigned short* p) {   // LDS or global
  return __builtin_bit_cast(bf16x8, *(const u16x8*)p);
}
__device__ __forceinline__ float ftanh(float x) {
  float e = __builtin_amdgcn_exp2f(x * 2.885390081777927f);
  return (e - 1.0f) * __builtin_amdgcn_rcpf(e + 1.0f);
}

// ---------------- pack kernel: fragment-ordered bf16 weight images ----------
// Image = 624 fragments x 1024 B. Per q-net (312 frags):
//   w1eff frags [nt 26][ks 2]  (52): elem[lane][j] = W1eff[ks*32+(lane>>4)*8+j][nt*16+(lane&15)]
//     W1eff[k][c] = k<39 ? w1[6+k][c] : (k==39 ? b1[c] : 0); cols padded to 416.
//   w2 frags [nt 20][ks 13] (260): elem[lane][j] = w2[k][c] zero-padded (k<400, c<300; pads 416/320)
// Fragment f at ws_u16 + f*512 + lane*8 -- one coalesced 16B/lane read in mlp.
struct PackP { const float* qp[12]; unsigned short* ws; };

__global__ void pack_weights(PackP P) {
  const int gid = blockIdx.x * 512 + threadIdx.x;
  if (gid >= 624 * 64) return;
  const int lane = gid & 63, f = gid >> 6;
  const int q = f / 312, fl = f - q * 312;
  const float* w1 = P.qp[q * 6 + 0];
  const float* b1 = P.qp[q * 6 + 1];
  const float* w2 = P.qp[q * 6 + 2];
  int nt, ks; const bool isw1 = (fl < 52);
  if (isw1) { nt = fl >> 1; ks = fl & 1; }
  else      { int fl2 = fl - 52; nt = fl2 / 13; ks = fl2 - nt * 13; }
  const int col = nt * 16 + (lane & 15);
  const int k0  = ks * 32 + (lane >> 4) * 8;
  unsigned short v[8];
  #pragma unroll
  for (int j = 0; j < 8; ++j) {
    const int k = k0 + j;
    float x = 0.f;
    if (isw1) {
      if (col < 400) {
        if (k < 39) x = w1[(6 + k) * 400 + col];
        else if (k == 39) x = b1[col];
      }
    } else {
      if (k < 400 && col < 300) x = w2[k * 300 + col];
    }
    v[j] = f2b(x);
  }
  *(u16x8*)(P.ws + (size_t)f * 512 + lane * 8) = *(const u16x8*)v;
}

// ---------------- phase-0 kernel: feature MLP -> xum bf16[B][64] (R8) --------
struct P0 {
  const float* state; const float* action;
  const float* f1w; const float* f1b;
  const float* f2w; const float* f2b;
  const float* f3w; const float* f3b;
  unsigned short* xum;
};

__global__ __launch_bounds__(PH_THR, 4) void phase0_kernel(P0 P) {
  __shared__ float w0[W0_FLOATS];
  __shared__ unsigned short hx[PH_ROWS * 68];
  const int tid = threadIdx.x;
  const int row = tid >> 2, sub = tid & 3, j0 = sub * 16;
  const long grow = (long)blockIdx.x * PH_ROWS + row;

  for (int i = tid; i < 528;  i += PH_THR) *(f32x4*)(w0 + F1W + 4*i) = *(const f32x4*)(P.f1w + 4*i);
  for (int i = tid; i < 16;   i += PH_THR) *(f32x4*)(w0 + F1B + 4*i) = *(const f32x4*)(P.f1b + 4*i);
  for (int i = tid; i < 1024; i += PH_THR) *(f32x4*)(w0 + F2W + 4*i) = *(const f32x4*)(P.f2w + 4*i);
  for (int i = tid; i < 16;   i += PH_THR) *(f32x4*)(w0 + F2B + 4*i) = *(const f32x4*)(P.f2b + 4*i);
  for (int i = tid; i < 512;  i += PH_THR) *(f32x4*)(w0 + F3W + 4*i) = *(const f32x4*)(P.f3w + 4*i);
  for (int i = tid; i < 8;    i += PH_THR) *(f32x4*)(w0 + F3B + 4*i) = *(const f32x4*)(P.f3b + 4*i);

  float sa[33];
  {
    const float4* sp = (const float4*)(P.state + grow * 32);
    #pragma unroll
    for (int c = 0; c < 8; ++c) {
      float4 v = sp[c];
      sa[c*4+0] = v.x; sa[c*4+1] = v.y; sa[c*4+2] = v.z; sa[c*4+3] = v.w;
    }
    sa[32] = P.action[grow];
  }
  __syncthreads();

  float acc[16];
  #pragma unroll
  for (int j = 0; j < 16; ++j) acc[j] = w0[F1B + j0 + j];
  #pragma unroll 4
  for (int i = 0; i < 33; ++i) {
    const float s = sa[i];
    const f32x4* wr = (const f32x4*)&w0[F1W + i * 64 + j0];
    #pragma unroll
    for (int c = 0; c < 4; ++c) {
      f32x4 wv = wr[c];
      acc[c*4+0] += s * wv[0]; acc[c*4+1] += s * wv[1];
      acc[c*4+2] += s * wv[2]; acc[c*4+3] += s * wv[3];
    }
  }
  {
    float ss = 0.f;
    #pragma unroll
    for (int j = 0; j < 16; ++j) ss += acc[j] * acc[j];
    ss += __shfl_xor(ss, 1, 64); ss += __shfl_xor(ss, 2, 64);
    const float sc = 1.f / fmaxf(sqrtf(ss), 1e-12f);
    #pragma unroll
    for (int j = 0; j < 16; ++j) hx[row * 68 + j0 + j] = f2b(ftanh(acc[j] * sc));
  }
  __syncthreads();
  #pragma unroll
  for (int j = 0; j < 16; ++j) acc[j] = w0[F2B + j0 + j];
  #pragma unroll 4
  for (int i = 0; i < 64; ++i) {
    const float hv = b2f(hx[row * 68 + i]);
    const f32x4* wr = (const f32x4*)&w0[F2W + i * 64 + j0];
    #pragma unroll
    for (int c = 0; c < 4; ++c) {
      f32x4 wv = wr[c];
      acc[c*4+0] += hv * wv[0]; acc[c*4+1] += hv * wv[1];
      acc[c*4+2] += hv * wv[2]; acc[c*4+3] += hv * wv[3];
    }
  }
  __syncthreads();
  #pragma unroll
  for (int j = 0; j < 16; ++j) hx[row * 68 + j0 + j] = f2b(ftanh(acc[j]));
  __syncthreads();
  const int j0m = sub * 8;
  float am[8];
  #pragma unroll
  for (int j = 0; j < 8; ++j) am[j] = w0[F3B + j0m + j];
  #pragma unroll 4
  for (int i = 0; i < 64; ++i) {
    const float hv = b2f(hx[row * 68 + i]);
    const f32x4* wr = (const f32x4*)&w0[F3W + i * 32 + j0m];
    #pragma unroll
    for (int c = 0; c < 2; ++c) {
      f32x4 wv = wr[c];
      am[c*4+0] += hv * wv[0]; am[c*4+1] += hv * wv[1];
      am[c*4+2] += hv * wv[2]; am[c*4+3] += hv * wv[3];
    }
  }
  float sm = 0.f;
  #pragma unroll
  for (int j = 0; j < 8; ++j) sm += am[j] * am[j];
  sm += __shfl_xor(sm, 1, 64); sm += __shfl_xor(sm, 2, 64);
  const float scm = 1.f / fmaxf(sqrtf(sm), 1e-12f);
  __syncthreads();
  #pragma unroll
  for (int j = 0; j < 8; ++j) hx[row * 68 + j0m + j] = f2b(am[j] * scm);
  __syncthreads();
  {
    u16x8 v0, v1;
    #pragma unroll
    for (int t = 0; t < 16; ++t) {
      const int c = j0 + t;
      unsigned short u;
      if      (c < 3)  u = f2b(sa[c]);
      else if (c < 6)  u = f2b(sa[c - 3]);
      else if (c < 38) u = hx[row * 68 + (c - 6)];
      else if (c == 38) u = f2b(sa[32]);
      else if (c == 39) u = 0x3f80;
      else              u = 0;
      if (t < 8) v0[t] = u; else v1[t - 8] = u;
    }
    unsigned short* dst = P.xum + (size_t)grow * 64 + j0;
    *(u16x8*)dst = v0;
    *(u16x8*)(dst + 8) = v1;
  }
}

// ---------------- mlp kernel: barrier-free k-loop, B-frags from L2 ----------
struct P1 {
  const unsigned short* img; const unsigned short* xum;
  const float* q1b2; const float* q1w3; const float* q1b3;
  const float* q2b2; const float* q2w3; const float* q2b3;
  float* out;
};

__global__ __launch_bounds__(ML_THR) void mlp_kernel(P1 P) {
  __shared__ __align__(16) unsigned short h1[ML_ROWS * H1S]; // 112,640 B
  __shared__ float xred[ML_ROWS * 4];                        //   2,048 B

  const int tid  = threadIdx.x;
  const int lane = tid & 63, w = tid >> 6;        // 16 waves
  const int rl = lane & 15, g = lane >> 4;

  // layer1 mapping: wave -> row-tile r1 (16 rows), col-half ch (13 nt of 16)
  const int r1 = w & 7, ch = w >> 3;
  // layer2 mapping: wave -> 32-row band wm, 80-col quarter wn (5 nt)
  const int wm = w >> 2, wn = w & 3;

  // A-fragments from xum (global, coalesced; reused by both q-nets)
  const unsigned short* xr = P.xum + ((size_t)blockIdx.x * ML_ROWS + r1 * 16 + rl) * 64;
  const bf16x8 af0 = ld8(xr + g * 8);
  const bf16x8 af1 = ld8(xr + 32 + g * 8);

  for (int q = 0; q < 2; ++q) {
    // ---- layer1: h1[128][400pad416] = relu(xum @ W1eff), bias folded ----
    {
      const unsigned short* w1f = P.img + ((size_t)(q * 312 + ch * 26)) * 512 + lane * 8;
      for (int t = 0; t < 13; ++t) {
        const bf16x8 b0 = ld8(w1f + (size_t)(t * 2) * 512);
        const bf16x8 b1 = ld8(w1f + (size_t)(t * 2 + 1) * 512);
        f32x4 a = (f32x4){0.f, 0.f, 0.f, 0.f};
        a = MFMA(af0, b0, a);
        a = MFMA(af1, b1, a);
        const int nt = ch * 13 + t;
        #pragma unroll
        for (int i = 0; i < 4; ++i)
          h1[(r1 * 16 + g * 4 + i) * H1S + nt * 16 + rl] = f2b(fmaxf(a[i], 0.f));
      }
    }
    __syncthreads();                              // h1 complete

    // ---- layer2: acc over K=416 (13 ks), B-frags straight from L2 ----
    f32x4 acc2[2][5];
    #pragma unroll
    for (int mt = 0; mt < 2; ++mt)
      #pragma unroll
      for (int jn = 0; jn < 5; ++jn) acc2[mt][jn] = (f32x4){0.f, 0.f, 0.f, 0.f};
    {
      const unsigned short* w2f = P.img + ((size_t)(q * 312 + 52 + wn * 5 * 13)) * 512 + lane * 8;
      #pragma unroll 2
      for (int ks = 0; ks < 13; ++ks) {
        const bf16x8 a0 = ld8(&h1[(wm * 32 + rl) * H1S + ks * 32 + g * 8]);
        const bf16x8 a1 = ld8(&h1[(wm * 32 + 16 + rl) * H1S + ks * 32 + g * 8]);
        #pragma unroll
        for (int jn = 0; jn < 5; ++jn) {
          const bf16x8 b = ld8(w2f + (size_t)(jn * 13 + ks) * 512);
          acc2[0][jn] = MFMA(a0, b, acc2[0][jn]);
          acc2[1][jn] = MFMA(a1, b, acc2[1][jn]);
        }
      }
    }

    // ---- epilogue: x = sum_n relu(h2+b2)*w3 + b3 ----
    const float* b2p = q ? P.q2b2 : P.q1b2;
    const float* w3  = q ? P.q2w3 : P.q1w3;
    const float* b3  = q ? P.q2b3 : P.q1b3;
    float xp[2][4];
    #pragma unroll
    for (int mt = 0; mt < 2; ++mt)
      #pragma unroll
      for (int i = 0; i < 4; ++i) xp[mt][i] = 0.f;
    #pragma unroll
    for (int jn = 0; jn < 5; ++jn) {
      const int n = wn * 80 + jn * 16 + rl;
      if (n < 300) {
        const float bv = b2p[n], wv = w3[n];
        #pragma unroll
        for (int mt = 0; mt < 2; ++mt)
          #pragma unroll
          for (int i = 0; i < 4; ++i)
            xp[mt][i] += fmaxf(acc2[mt][jn][i] + bv, 0.f) * wv;
      }
    }
    #pragma unroll
    for (int off = 1; off < 16; off <<= 1)
      #pragma unroll
      for (int mt = 0; mt < 2; ++mt)
        #pragma unroll
        for (int i = 0; i < 4; ++i)
          xp[mt][i] += __shfl_xor(xp[mt][i], off, 64);
    if (rl == 0) {
      #pragma unroll
      for (int mt = 0; mt < 2; ++mt)
        #pragma unroll
        for (int i = 0; i < 4; ++i)
          xred[(wm * 32 + mt * 16 + g * 4 + i) * 4 + wn] = xp[mt][i];
    }
    __syncthreads();                              // xred visible; h1 reads done
    if (tid < ML_ROWS) {
      const float4 xv = *(const float4*)&xred[tid * 4];
      P.out[(size_t)q * BTOT + (size_t)blockIdx.x * ML_ROWS + tid] =
          xv.x + xv.y + xv.z + xv.w + b3[0];
    }
    __syncthreads();                              // out read of xred done; h1 reusable
  }
}

extern "C" void kernel_launch(void* const* d_in, const int* in_sizes, int n_in,
                              void* d_out, int out_size, void* d_ws, size_t ws_size,
                              hipStream_t stream) {
  (void)in_sizes; (void)n_in; (void)out_size; (void)ws_size;
  PackP K;
  for (int i = 0; i < 12; ++i) K.qp[i] = (const float*)d_in[10 + i];
  K.ws = (unsigned short*)d_ws;
  pack_weights<<<dim3(78), dim3(512), 0, stream>>>(K);

  P0 A;
  A.state  = (const float*)d_in[0];
  A.action = (const float*)d_in[1];
  A.f1w = (const float*)d_in[2]; A.f1b = (const float*)d_in[3];
  A.f2w = (const float*)d_in[4]; A.f2b = (const float*)d_in[5];
  A.f3w = (const float*)d_in[6]; A.f3b = (const float*)d_in[7];
  A.xum = (unsigned short*)((unsigned char*)d_ws + XUM_OFF);
  phase0_kernel<<<dim3(PH_BLK), dim3(PH_THR), 0, stream>>>(A);

  P1 B;
  B.img  = (const unsigned short*)d_ws;
  B.xum  = (const unsigned short*)((unsigned char*)d_ws + XUM_OFF);
  B.q1b2 = (const float*)d_in[13]; B.q1w3 = (const float*)d_in[14]; B.q1b3 = (const float*)d_in[15];
  B.q2b2 = (const float*)d_in[19]; B.q2w3 = (const float*)d_in[20]; B.q2b3 = (const float*)d_in[21];
  B.out  = (float*)d_out;
  mlp_kernel<<<dim3(ML_BLK), dim3(ML_THR), 0, stream>>>(B);
}

// Round 10
// 112.200 us; speedup vs baseline: 1.4071x; 1.0113x over previous
//
#include <hip/hip_runtime.h>
#include <math.h>

// CriticGraphPolicy, MI355X (gfx950). Round 10.
// R9 post-mortem: mlp at 22% MfmaUtil; VALU (f2b bit-ops) + 4 scattered
// ds_write_b16 per layer1 t-iter + rolled loops are the residue. R10:
//   - layer1 MFMA operand SWAP (A=W1 frag, B=xum frag; layouts identical)
//     -> lane holds 4 consecutive cols for fixed row -> relu + 2x
//     v_cvt_pk_bf16_f32 + ONE ds_write_b64 (h1 now [row][col], stride 424)
//   - unroll hints for load pipelining
//   - pack_weights fused into phase0 grid (blocks 0..77) -- one less launch
//   - phase0 hx reads vectorized (u16x4)

#define BTOT   65536
#define XUM_OFF 655360ull        // xum offset in d_ws (frag img = 638,976 B)

// phase0 (+fused pack)
#define PK_BLK  78               // 78*512 = 624 frags * 64 lanes
#define PH_THR  512
#define PH_ROWS 128
#define PH_BLK  (BTOT / PH_ROWS) // 512
#define F1W 0
#define F1B 2112
#define F2W 2176
#define F2B 6272
#define F3W 6336
#define F3B 8384
#define W0_FLOATS 8416

// mlp
#define ML_THR  1024
#define ML_ROWS 128
#define ML_BLK  (BTOT / ML_ROWS) // 512
#define H1S     424              // h1 col stride (u16): 848B rows -> 2-way banks, 8B-aligned

typedef float  f32x4 __attribute__((ext_vector_type(4)));
typedef __bf16 bf16x8 __attribute__((ext_vector_type(8)));
typedef unsigned short u16x8 __attribute__((ext_vector_type(8)));
typedef unsigned short u16x4 __attribute__((ext_vector_type(4)));
typedef unsigned int   u32x2 __attribute__((ext_vector_type(2)));

__device__ __forceinline__ unsigned short f2b(float f) {
  union { float f; unsigned int u; } v; v.f = f;
  return (unsigned short)((v.u + 0x7fffu + ((v.u >> 16) & 1u)) >> 16);
}
__device__ __forceinline__ float b2f(unsigned short u) {
  union { unsigned int u; float f; } v; v.u = ((unsigned int)u) << 16;
  return v.f;
}
__device__ __forceinline__ f32x4 MFMA(bf16x8 a, bf16x8 b, f32x4 c) {
  return __builtin_amdgcn_mfma_f32_16x16x32_bf16(a, b, c, 0, 0, 0);
}
__device__ __forceinline__ bf16x8 ld8(const unsigned short* p) {
  return __builtin_bit_cast(bf16x8, *(const u16x8*)p);
}
__device__ __forceinline__ float ftanh(float x) {
  float e = __builtin_amdgcn_exp2f(x * 2.885390081777927f);
  return (e - 1.0f) * __builtin_amdgcn_rcpf(e + 1.0f);
}

// ---------------- phase0 kernel (+fused fragment pack) ----------------
// pack image = 624 fragments x 1024 B (q-net: 312 = w1eff [nt 26][ks 2] then
// w2 [nt 20][ks 13]); frag elem[lane][j] = W[k0+j][col], col=nt*16+(lane&15),
// k0=ks*32+(lane>>4)*8. One coalesced 16B/lane read per frag in mlp.
struct P0 {
  const float* state; const float* action;
  const float* f1w; const float* f1b;
  const float* f2w; const float* f2b;
  const float* f3w; const float* f3b;
  const float* q1w1; const float* q1b1; const float* q1w2;
  const float* q2w1; const float* q2b1; const float* q2w2;
  unsigned short* ws;    // frag image
  unsigned short* xum;   // bf16 [B][64]
};

__global__ __launch_bounds__(PH_THR, 4) void phase0_kernel(P0 P) {
  __shared__ float w0[W0_FLOATS];
  __shared__ unsigned short hx[PH_ROWS * 68];
  const int tid = threadIdx.x;

  if (blockIdx.x < PK_BLK) {          // ---- fragment pack path ----
    const int gid = blockIdx.x * PH_THR + tid;   // < 39936 exactly
    const int lane = gid & 63, f = gid >> 6;
    const int q = f / 312, fl = f - q * 312;
    const float* w1 = q ? P.q2w1 : P.q1w1;
    const float* b1 = q ? P.q2b1 : P.q1b1;
    const float* w2 = q ? P.q2w2 : P.q1w2;
    int nt, ks; const bool isw1 = (fl < 52);
    if (isw1) { nt = fl >> 1; ks = fl & 1; }
    else      { int fl2 = fl - 52; nt = fl2 / 13; ks = fl2 - nt * 13; }
    const int col = nt * 16 + (lane & 15);
    const int k0  = ks * 32 + (lane >> 4) * 8;
    unsigned short v[8];
    #pragma unroll
    for (int j = 0; j < 8; ++j) {
      const int k = k0 + j;
      float x = 0.f;
      if (isw1) {
        if (col < 400) {
          if (k < 39) x = w1[(6 + k) * 400 + col];
          else if (k == 39) x = b1[col];
        }
      } else {
        if (k < 400 && col < 300) x = w2[k * 300 + col];
      }
      v[j] = f2b(x);
    }
    *(u16x8*)(P.ws + (size_t)f * 512 + lane * 8) = *(const u16x8*)v;
    return;
  }

  // ---- feature-MLP path ----
  const int row = tid >> 2, sub = tid & 3, j0 = sub * 16;
  const long grow = (long)(blockIdx.x - PK_BLK) * PH_ROWS + row;

  for (int i = tid; i < 528;  i += PH_THR) *(f32x4*)(w0 + F1W + 4*i) = *(const f32x4*)(P.f1w + 4*i);
  for (int i = tid; i < 16;   i += PH_THR) *(f32x4*)(w0 + F1B + 4*i) = *(const f32x4*)(P.f1b + 4*i);
  for (int i = tid; i < 1024; i += PH_THR) *(f32x4*)(w0 + F2W + 4*i) = *(const f32x4*)(P.f2w + 4*i);
  for (int i = tid; i < 16;   i += PH_THR) *(f32x4*)(w0 + F2B + 4*i) = *(const f32x4*)(P.f2b + 4*i);
  for (int i = tid; i < 512;  i += PH_THR) *(f32x4*)(w0 + F3W + 4*i) = *(const f32x4*)(P.f3w + 4*i);
  for (int i = tid; i < 8;    i += PH_THR) *(f32x4*)(w0 + F3B + 4*i) = *(const f32x4*)(P.f3b + 4*i);

  float sa[33];
  {
    const float4* sp = (const float4*)(P.state + grow * 32);
    #pragma unroll
    for (int c = 0; c < 8; ++c) {
      float4 v = sp[c];
      sa[c*4+0] = v.x; sa[c*4+1] = v.y; sa[c*4+2] = v.z; sa[c*4+3] = v.w;
    }
    sa[32] = P.action[grow];
  }
  __syncthreads();

  float acc[16];
  // fc1
  #pragma unroll
  for (int j = 0; j < 16; ++j) acc[j] = w0[F1B + j0 + j];
  #pragma unroll 4
  for (int i = 0; i < 33; ++i) {
    const float s = sa[i];
    const f32x4* wr = (const f32x4*)&w0[F1W + i * 64 + j0];
    #pragma unroll
    for (int c = 0; c < 4; ++c) {
      f32x4 wv = wr[c];
      acc[c*4+0] += s * wv[0]; acc[c*4+1] += s * wv[1];
      acc[c*4+2] += s * wv[2]; acc[c*4+3] += s * wv[3];
    }
  }
  {
    float ss = 0.f;
    #pragma unroll
    for (int j = 0; j < 16; ++j) ss += acc[j] * acc[j];
    ss += __shfl_xor(ss, 1, 64); ss += __shfl_xor(ss, 2, 64);
    const float sc = 1.f / fmaxf(sqrtf(ss), 1e-12f);
    #pragma unroll
    for (int j = 0; j < 16; ++j) hx[row * 68 + j0 + j] = f2b(ftanh(acc[j] * sc));
  }
  __syncthreads();
  // fc2 (vectorized hx reads)
  #pragma unroll
  for (int j = 0; j < 16; ++j) acc[j] = w0[F2B + j0 + j];
  #pragma unroll 4
  for (int i0 = 0; i0 < 16; ++i0) {
    const u16x4 hv4 = *(const u16x4*)&hx[row * 68 + i0 * 4];
    #pragma unroll
    for (int u = 0; u < 4; ++u) {
      const float hv = b2f(hv4[u]);
      const f32x4* wr = (const f32x4*)&w0[F2W + (i0 * 4 + u) * 64 + j0];
      #pragma unroll
      for (int c = 0; c < 4; ++c) {
        f32x4 wv = wr[c];
        acc[c*4+0] += hv * wv[0]; acc[c*4+1] += hv * wv[1];
        acc[c*4+2] += hv * wv[2]; acc[c*4+3] += hv * wv[3];
      }
    }
  }
  __syncthreads();
  #pragma unroll
  for (int j = 0; j < 16; ++j) hx[row * 68 + j0 + j] = f2b(ftanh(acc[j]));
  __syncthreads();
  // fc3 (vectorized hx reads)
  const int j0m = sub * 8;
  float am[8];
  #pragma unroll
  for (int j = 0; j < 8; ++j) am[j] = w0[F3B + j0m + j];
  #pragma unroll 4
  for (int i0 = 0; i0 < 16; ++i0) {
    const u16x4 hv4 = *(const u16x4*)&hx[row * 68 + i0 * 4];
    #pragma unroll
    for (int u = 0; u < 4; ++u) {
      const float hv = b2f(hv4[u]);
      const f32x4* wr = (const f32x4*)&w0[F3W + (i0 * 4 + u) * 32 + j0m];
      #pragma unroll
      for (int c = 0; c < 2; ++c) {
        f32x4 wv = wr[c];
        am[c*4+0] += hv * wv[0]; am[c*4+1] += hv * wv[1];
        am[c*4+2] += hv * wv[2]; am[c*4+3] += hv * wv[3];
      }
    }
  }
  float sm = 0.f;
  #pragma unroll
  for (int j = 0; j < 8; ++j) sm += am[j] * am[j];
  sm += __shfl_xor(sm, 1, 64); sm += __shfl_xor(sm, 2, 64);
  const float scm = 1.f / fmaxf(sqrtf(sm), 1e-12f);
  __syncthreads();
  #pragma unroll
  for (int j = 0; j < 8; ++j) hx[row * 68 + j0m + j] = f2b(am[j] * scm);
  __syncthreads();
  {
    u16x8 v0, v1;
    #pragma unroll
    for (int t = 0; t < 16; ++t) {
      const int c = j0 + t;
      unsigned short u;
      if      (c < 3)  u = f2b(sa[c]);
      else if (c < 6)  u = f2b(sa[c - 3]);
      else if (c < 38) u = hx[row * 68 + (c - 6)];
      else if (c == 38) u = f2b(sa[32]);
      else if (c == 39) u = 0x3f80;
      else              u = 0;
      if (t < 8) v0[t] = u; else v1[t - 8] = u;
    }
    unsigned short* dst = P.xum + (size_t)grow * 64 + j0;
    *(u16x8*)dst = v0;
    *(u16x8*)(dst + 8) = v1;
  }
}

// ---------------- mlp kernel ----------------
struct P1 {
  const unsigned short* img; const unsigned short* xum;
  const float* q1b2; const float* q1w3; const float* q1b3;
  const float* q2b2; const float* q2w3; const float* q2b3;
  float* out;
};

__global__ __launch_bounds__(ML_THR) void mlp_kernel(P1 P) {
  __shared__ __align__(16) unsigned short h1[ML_ROWS * H1S]; // 108,544 B
  __shared__ float xred[ML_ROWS * 4];                        //   2,048 B

  const int tid  = threadIdx.x;
  const int lane = tid & 63, w = tid >> 6;        // 16 waves
  const int rl = lane & 15, g = lane >> 4;

  const int r1 = w & 7, ch = w >> 3;              // layer1: 8 row-tiles x 2 col-halves
  const int wm = w >> 2, wn = w & 3;              // layer2: 4 row-bands x 4 col-quarters

  // xum fragments (per-wave 16 rows; used as the B operand of swapped layer1)
  const unsigned short* xr = P.xum + ((size_t)blockIdx.x * ML_ROWS + r1 * 16 + rl) * 64;
  const bf16x8 af0 = ld8(xr + g * 8);
  const bf16x8 af1 = ld8(xr + 32 + g * 8);

  for (int q = 0; q < 2; ++q) {
    // ---- layer1 (SWAPPED): D[c][r]; lane holds r=rl, c=g*4+0..3 ----
    {
      const unsigned short* w1f = P.img + ((size_t)(q * 312 + ch * 26)) * 512 + lane * 8;
      unsigned short* h1w = &h1[(size_t)(r1 * 16 + rl) * H1S + ch * 208 + g * 4];
      #pragma unroll 4
      for (int t = 0; t < 13; ++t) {
        const bf16x8 b0 = ld8(w1f + (size_t)(t * 2) * 512);
        const bf16x8 b1 = ld8(w1f + (size_t)(t * 2 + 1) * 512);
        f32x4 a = (f32x4){0.f, 0.f, 0.f, 0.f};
        a = MFMA(b0, af0, a);                     // A=W1^T frag, B=xum frag
        a = MFMA(b1, af1, a);
        const float c0 = fmaxf(a[0], 0.f), c1 = fmaxf(a[1], 0.f);
        const float c2 = fmaxf(a[2], 0.f), c3 = fmaxf(a[3], 0.f);
        unsigned int p01, p23;
        asm("v_cvt_pk_bf16_f32 %0, %1, %2" : "=v"(p01) : "v"(c0), "v"(c1));
        asm("v_cvt_pk_bf16_f32 %0, %1, %2" : "=v"(p23) : "v"(c2), "v"(c3));
        u32x2 pk; pk[0] = p01; pk[1] = p23;
        *(u32x2*)(h1w + t * 16) = pk;             // one b64 write, 4 cols
      }
    }
    __syncthreads();                              // h1 complete

    // ---- layer2: K=416 (13 ks), B-frags from L2, A from LDS ----
    f32x4 acc2[2][5];
    #pragma unroll
    for (int mt = 0; mt < 2; ++mt)
      #pragma unroll
      for (int jn = 0; jn < 5; ++jn) acc2[mt][jn] = (f32x4){0.f, 0.f, 0.f, 0.f};
    {
      const unsigned short* w2f = P.img + ((size_t)(q * 312 + 52 + wn * 65)) * 512 + lane * 8;
      #pragma unroll 2
      for (int ks = 0; ks < 13; ++ks) {
        const bf16x8 a0 = ld8(&h1[(size_t)(wm * 32 + rl) * H1S + ks * 32 + g * 8]);
        const bf16x8 a1 = ld8(&h1[(size_t)(wm * 32 + 16 + rl) * H1S + ks * 32 + g * 8]);
        #pragma unroll
        for (int jn = 0; jn < 5; ++jn) {
          const bf16x8 b = ld8(w2f + (size_t)(jn * 13 + ks) * 512);
          acc2[0][jn] = MFMA(a0, b, acc2[0][jn]);
          acc2[1][jn] = MFMA(a1, b, acc2[1][jn]);
        }
      }
    }

    // ---- epilogue ----
    const float* b2p = q ? P.q2b2 : P.q1b2;
    const float* w3  = q ? P.q2w3 : P.q1w3;
    const float* b3  = q ? P.q2b3 : P.q1b3;
    float xp[2][4];
    #pragma unroll
    for (int mt = 0; mt < 2; ++mt)
      #pragma unroll
      for (int i = 0; i < 4; ++i) xp[mt][i] = 0.f;
    #pragma unroll
    for (int jn = 0; jn < 5; ++jn) {
      const int n = wn * 80 + jn * 16 + rl;
      if (n < 300) {
        const float bv = b2p[n], wv = w3[n];
        #pragma unroll
        for (int mt = 0; mt < 2; ++mt)
          #pragma unroll
          for (int i = 0; i < 4; ++i)
            xp[mt][i] += fmaxf(acc2[mt][jn][i] + bv, 0.f) * wv;
      }
    }
    #pragma unroll
    for (int off = 1; off < 16; off <<= 1)
      #pragma unroll
      for (int mt = 0; mt < 2; ++mt)
        #pragma unroll
        for (int i = 0; i < 4; ++i)
          xp[mt][i] += __shfl_xor(xp[mt][i], off, 64);
    if (rl == 0) {
      #pragma unroll
      for (int mt = 0; mt < 2; ++mt)
        #pragma unroll
        for (int i = 0; i < 4; ++i)
          xred[(wm * 32 + mt * 16 + g * 4 + i) * 4 + wn] = xp[mt][i];
    }
    __syncthreads();                              // xred visible; h1 reads done
    if (tid < ML_ROWS) {
      const float4 xv = *(const float4*)&xred[tid * 4];
      P.out[(size_t)q * BTOT + (size_t)blockIdx.x * ML_ROWS + tid] =
          xv.x + xv.y + xv.z + xv.w + b3[0];
    }
    __syncthreads();                              // xred read done; h1 reusable
  }
}

extern "C" void kernel_launch(void* const* d_in, const int* in_sizes, int n_in,
                              void* d_out, int out_size, void* d_ws, size_t ws_size,
                              hipStream_t stream) {
  (void)in_sizes; (void)n_in; (void)out_size; (void)ws_size;
  P0 A;
  A.state  = (const float*)d_in[0];
  A.action = (const float*)d_in[1];
  A.f1w = (const float*)d_in[2]; A.f1b = (const float*)d_in[3];
  A.f2w = (const float*)d_in[4]; A.f2b = (const float*)d_in[5];
  A.f3w = (const float*)d_in[6]; A.f3b = (const float*)d_in[7];
  A.q1w1 = (const float*)d_in[10]; A.q1b1 = (const float*)d_in[11]; A.q1w2 = (const float*)d_in[12];
  A.q2w1 = (const float*)d_in[16]; A.q2b1 = (const float*)d_in[17]; A.q2w2 = (const float*)d_in[18];
  A.ws  = (unsigned short*)d_ws;
  A.xum = (unsigned short*)((unsigned char*)d_ws + XUM_OFF);
  phase0_kernel<<<dim3(PK_BLK + PH_BLK), dim3(PH_THR), 0, stream>>>(A);

  P1 B;
  B.img  = (const unsigned short*)d_ws;
  B.xum  = (const unsigned short*)((unsigned char*)d_ws + XUM_OFF);
  B.q1b2 = (const float*)d_in[13]; B.q1w3 = (const float*)d_in[14]; B.q1b3 = (const float*)d_in[15];
  B.q2b2 = (const float*)d_in[19]; B.q2w3 = (const float*)d_in[20]; B.q2b3 = (const float*)d_in[21];
  B.out  = (float*)d_out;
  mlp_kernel<<<dim3(ML_BLK), dim3(ML_THR), 0, stream>>>(B);
}

// Round 11
// 112.166 us; speedup vs baseline: 1.4075x; 1.0003x over previous
//
#include <hip/hip_runtime.h>
#include <math.h>

// CriticGraphPolicy, MI355X (gfx950). Round 11.
// R10 post-mortem: VALU cut didn't move time -> stall is L2 fragment-load
// latency; compiler pipelines loads only ~1 shallow despite VGPR 56/128.
// R11: explicit depth-2 software pipeline (named bA/bB register buffers,
// static indices) for layer1 and layer2 fragment loads; h1 stride 424->428
// (4-way -> 2-way banks). phase0 unchanged from R10.

#define BTOT   65536
#define XUM_OFF 655360ull        // xum offset in d_ws (frag img = 638,976 B)

// phase0 (+fused pack)
#define PK_BLK  78
#define PH_THR  512
#define PH_ROWS 128
#define PH_BLK  (BTOT / PH_ROWS)
#define F1W 0
#define F1B 2112
#define F2W 2176
#define F2B 6272
#define F3W 6336
#define F3B 8384
#define W0_FLOATS 8416

// mlp
#define ML_THR  1024
#define ML_ROWS 128
#define ML_BLK  (BTOT / ML_ROWS)
#define H1S     428              // u16 stride: 856B rows -> 2-way banks, 8B-aligned

typedef float  f32x4 __attribute__((ext_vector_type(4)));
typedef __bf16 bf16x8 __attribute__((ext_vector_type(8)));
typedef unsigned short u16x8 __attribute__((ext_vector_type(8)));
typedef unsigned short u16x4 __attribute__((ext_vector_type(4)));
typedef unsigned int   u32x2 __attribute__((ext_vector_type(2)));

__device__ __forceinline__ unsigned short f2b(float f) {
  union { float f; unsigned int u; } v; v.f = f;
  return (unsigned short)((v.u + 0x7fffu + ((v.u >> 16) & 1u)) >> 16);
}
__device__ __forceinline__ float b2f(unsigned short u) {
  union { unsigned int u; float f; } v; v.u = ((unsigned int)u) << 16;
  return v.f;
}
__device__ __forceinline__ f32x4 MFMA(bf16x8 a, bf16x8 b, f32x4 c) {
  return __builtin_amdgcn_mfma_f32_16x16x32_bf16(a, b, c, 0, 0, 0);
}
__device__ __forceinline__ bf16x8 ld8(const unsigned short* p) {
  return __builtin_bit_cast(bf16x8, *(const u16x8*)p);
}
__device__ __forceinline__ float ftanh(float x) {
  float e = __builtin_amdgcn_exp2f(x * 2.885390081777927f);
  return (e - 1.0f) * __builtin_amdgcn_rcpf(e + 1.0f);
}

// ---------------- phase0 kernel (+fused fragment pack) ----------------
struct P0 {
  const float* state; const float* action;
  const float* f1w; const float* f1b;
  const float* f2w; const float* f2b;
  const float* f3w; const float* f3b;
  const float* q1w1; const float* q1b1; const float* q1w2;
  const float* q2w1; const float* q2b1; const float* q2w2;
  unsigned short* ws;    // frag image
  unsigned short* xum;   // bf16 [B][64]
};

__global__ __launch_bounds__(PH_THR, 4) void phase0_kernel(P0 P) {
  __shared__ float w0[W0_FLOATS];
  __shared__ unsigned short hx[PH_ROWS * 68];
  const int tid = threadIdx.x;

  if (blockIdx.x < PK_BLK) {          // ---- fragment pack path ----
    const int gid = blockIdx.x * PH_THR + tid;
    const int lane = gid & 63, f = gid >> 6;
    const int q = f / 312, fl = f - q * 312;
    const float* w1 = q ? P.q2w1 : P.q1w1;
    const float* b1 = q ? P.q2b1 : P.q1b1;
    const float* w2 = q ? P.q2w2 : P.q1w2;
    int nt, ks; const bool isw1 = (fl < 52);
    if (isw1) { nt = fl >> 1; ks = fl & 1; }
    else      { int fl2 = fl - 52; nt = fl2 / 13; ks = fl2 - nt * 13; }
    const int col = nt * 16 + (lane & 15);
    const int k0  = ks * 32 + (lane >> 4) * 8;
    unsigned short v[8];
    #pragma unroll
    for (int j = 0; j < 8; ++j) {
      const int k = k0 + j;
      float x = 0.f;
      if (isw1) {
        if (col < 400) {
          if (k < 39) x = w1[(6 + k) * 400 + col];
          else if (k == 39) x = b1[col];
        }
      } else {
        if (k < 400 && col < 300) x = w2[k * 300 + col];
      }
      v[j] = f2b(x);
    }
    *(u16x8*)(P.ws + (size_t)f * 512 + lane * 8) = *(const u16x8*)v;
    return;
  }

  // ---- feature-MLP path ----
  const int row = tid >> 2, sub = tid & 3, j0 = sub * 16;
  const long grow = (long)(blockIdx.x - PK_BLK) * PH_ROWS + row;

  for (int i = tid; i < 528;  i += PH_THR) *(f32x4*)(w0 + F1W + 4*i) = *(const f32x4*)(P.f1w + 4*i);
  for (int i = tid; i < 16;   i += PH_THR) *(f32x4*)(w0 + F1B + 4*i) = *(const f32x4*)(P.f1b + 4*i);
  for (int i = tid; i < 1024; i += PH_THR) *(f32x4*)(w0 + F2W + 4*i) = *(const f32x4*)(P.f2w + 4*i);
  for (int i = tid; i < 16;   i += PH_THR) *(f32x4*)(w0 + F2B + 4*i) = *(const f32x4*)(P.f2b + 4*i);
  for (int i = tid; i < 512;  i += PH_THR) *(f32x4*)(w0 + F3W + 4*i) = *(const f32x4*)(P.f3w + 4*i);
  for (int i = tid; i < 8;    i += PH_THR) *(f32x4*)(w0 + F3B + 4*i) = *(const f32x4*)(P.f3b + 4*i);

  float sa[33];
  {
    const float4* sp = (const float4*)(P.state + grow * 32);
    #pragma unroll
    for (int c = 0; c < 8; ++c) {
      float4 v = sp[c];
      sa[c*4+0] = v.x; sa[c*4+1] = v.y; sa[c*4+2] = v.z; sa[c*4+3] = v.w;
    }
    sa[32] = P.action[grow];
  }
  __syncthreads();

  float acc[16];
  #pragma unroll
  for (int j = 0; j < 16; ++j) acc[j] = w0[F1B + j0 + j];
  #pragma unroll 4
  for (int i = 0; i < 33; ++i) {
    const float s = sa[i];
    const f32x4* wr = (const f32x4*)&w0[F1W + i * 64 + j0];
    #pragma unroll
    for (int c = 0; c < 4; ++c) {
      f32x4 wv = wr[c];
      acc[c*4+0] += s * wv[0]; acc[c*4+1] += s * wv[1];
      acc[c*4+2] += s * wv[2]; acc[c*4+3] += s * wv[3];
    }
  }
  {
    float ss = 0.f;
    #pragma unroll
    for (int j = 0; j < 16; ++j) ss += acc[j] * acc[j];
    ss += __shfl_xor(ss, 1, 64); ss += __shfl_xor(ss, 2, 64);
    const float sc = 1.f / fmaxf(sqrtf(ss), 1e-12f);
    #pragma unroll
    for (int j = 0; j < 16; ++j) hx[row * 68 + j0 + j] = f2b(ftanh(acc[j] * sc));
  }
  __syncthreads();
  #pragma unroll
  for (int j = 0; j < 16; ++j) acc[j] = w0[F2B + j0 + j];
  #pragma unroll 4
  for (int i0 = 0; i0 < 16; ++i0) {
    const u16x4 hv4 = *(const u16x4*)&hx[row * 68 + i0 * 4];
    #pragma unroll
    for (int u = 0; u < 4; ++u) {
      const float hv = b2f(hv4[u]);
      const f32x4* wr = (const f32x4*)&w0[F2W + (i0 * 4 + u) * 64 + j0];
      #pragma unroll
      for (int c = 0; c < 4; ++c) {
        f32x4 wv = wr[c];
        acc[c*4+0] += hv * wv[0]; acc[c*4+1] += hv * wv[1];
        acc[c*4+2] += hv * wv[2]; acc[c*4+3] += hv * wv[3];
      }
    }
  }
  __syncthreads();
  #pragma unroll
  for (int j = 0; j < 16; ++j) hx[row * 68 + j0 + j] = f2b(ftanh(acc[j]));
  __syncthreads();
  const int j0m = sub * 8;
  float am[8];
  #pragma unroll
  for (int j = 0; j < 8; ++j) am[j] = w0[F3B + j0m + j];
  #pragma unroll 4
  for (int i0 = 0; i0 < 16; ++i0) {
    const u16x4 hv4 = *(const u16x4*)&hx[row * 68 + i0 * 4];
    #pragma unroll
    for (int u = 0; u < 4; ++u) {
      const float hv = b2f(hv4[u]);
      const f32x4* wr = (const f32x4*)&w0[F3W + (i0 * 4 + u) * 32 + j0m];
      #pragma unroll
      for (int c = 0; c < 2; ++c) {
        f32x4 wv = wr[c];
        am[c*4+0] += hv * wv[0]; am[c*4+1] += hv * wv[1];
        am[c*4+2] += hv * wv[2]; am[c*4+3] += hv * wv[3];
      }
    }
  }
  float sm = 0.f;
  #pragma unroll
  for (int j = 0; j < 8; ++j) sm += am[j] * am[j];
  sm += __shfl_xor(sm, 1, 64); sm += __shfl_xor(sm, 2, 64);
  const float scm = 1.f / fmaxf(sqrtf(sm), 1e-12f);
  __syncthreads();
  #pragma unroll
  for (int j = 0; j < 8; ++j) hx[row * 68 + j0m + j] = f2b(am[j] * scm);
  __syncthreads();
  {
    u16x8 v0, v1;
    #pragma unroll
    for (int t = 0; t < 16; ++t) {
      const int c = j0 + t;
      unsigned short u;
      if      (c < 3)  u = f2b(sa[c]);
      else if (c < 6)  u = f2b(sa[c - 3]);
      else if (c < 38) u = hx[row * 68 + (c - 6)];
      else if (c == 38) u = f2b(sa[32]);
      else if (c == 39) u = 0x3f80;
      else              u = 0;
      if (t < 8) v0[t] = u; else v1[t - 8] = u;
    }
    unsigned short* dst = P.xum + (size_t)grow * 64 + j0;
    *(u16x8*)dst = v0;
    *(u16x8*)(dst + 8) = v1;
  }
}

// ---------------- mlp kernel: depth-2 register-pipelined frag loads ---------
struct P1 {
  const unsigned short* img; const unsigned short* xum;
  const float* q1b2; const float* q1w3; const float* q1b3;
  const float* q2b2; const float* q2w3; const float* q2b3;
  float* out;
};

__global__ __launch_bounds__(ML_THR) void mlp_kernel(P1 P) {
  __shared__ __align__(16) unsigned short h1[ML_ROWS * H1S]; // 109,568 B
  __shared__ float xred[ML_ROWS * 4];

  const int tid  = threadIdx.x;
  const int lane = tid & 63, w = tid >> 6;        // 16 waves
  const int rl = lane & 15, g = lane >> 4;

  const int r1 = w & 7, ch = w >> 3;              // layer1: 8 row-tiles x 2 halves
  const int wm = w >> 2, wn = w & 3;              // layer2: 4 bands x 4 quarters

  const unsigned short* xr = P.xum + ((size_t)blockIdx.x * ML_ROWS + r1 * 16 + rl) * 64;
  const bf16x8 af0 = ld8(xr + g * 8);
  const bf16x8 af1 = ld8(xr + 32 + g * 8);

  for (int q = 0; q < 2; ++q) {
    // ---- layer1 (swapped operands), depth-2 pipelined W1 frag loads ----
    {
      const unsigned short* w1f = P.img + ((size_t)(q * 312 + ch * 26)) * 512 + lane * 8;
      unsigned short* h1w = &h1[(size_t)(r1 * 16 + rl) * H1S + ch * 208 + g * 4];
      bf16x8 wA0 = ld8(w1f + 0 * 512), wA1 = ld8(w1f + 1 * 512);
      bf16x8 wB0 = ld8(w1f + 2 * 512), wB1 = ld8(w1f + 3 * 512);
      for (int t = 0; t < 13; t += 2) {
        {
          f32x4 a = (f32x4){0.f, 0.f, 0.f, 0.f};
          a = MFMA(wA0, af0, a);
          a = MFMA(wA1, af1, a);
          if (t + 2 < 13) {
            wA0 = ld8(w1f + (size_t)((t + 2) * 2) * 512);
            wA1 = ld8(w1f + (size_t)((t + 2) * 2 + 1) * 512);
          }
          const float c0 = fmaxf(a[0], 0.f), c1 = fmaxf(a[1], 0.f);
          const float c2 = fmaxf(a[2], 0.f), c3 = fmaxf(a[3], 0.f);
          unsigned int p01, p23;
          asm("v_cvt_pk_bf16_f32 %0, %1, %2" : "=v"(p01) : "v"(c0), "v"(c1));
          asm("v_cvt_pk_bf16_f32 %0, %1, %2" : "=v"(p23) : "v"(c2), "v"(c3));
          u32x2 pk; pk[0] = p01; pk[1] = p23;
          *(u32x2*)(h1w + t * 16) = pk;
        }
        if (t + 1 < 13) {
          f32x4 a = (f32x4){0.f, 0.f, 0.f, 0.f};
          a = MFMA(wB0, af0, a);
          a = MFMA(wB1, af1, a);
          if (t + 3 < 13) {
            wB0 = ld8(w1f + (size_t)((t + 3) * 2) * 512);
            wB1 = ld8(w1f + (size_t)((t + 3) * 2 + 1) * 512);
          }
          const float c0 = fmaxf(a[0], 0.f), c1 = fmaxf(a[1], 0.f);
          const float c2 = fmaxf(a[2], 0.f), c3 = fmaxf(a[3], 0.f);
          unsigned int p01, p23;
          asm("v_cvt_pk_bf16_f32 %0, %1, %2" : "=v"(p01) : "v"(c0), "v"(c1));
          asm("v_cvt_pk_bf16_f32 %0, %1, %2" : "=v"(p23) : "v"(c2), "v"(c3));
          u32x2 pk; pk[0] = p01; pk[1] = p23;
          *(u32x2*)(h1w + (t + 1) * 16) = pk;
        }
      }
    }
    __syncthreads();                              // h1 complete

    // ---- layer2: K=416 (13 ks), depth-2 pipelined W2 frag loads ----
    f32x4 acc2[2][5];
    #pragma unroll
    for (int mt = 0; mt < 2; ++mt)
      #pragma unroll
      for (int jn = 0; jn < 5; ++jn) acc2[mt][jn] = (f32x4){0.f, 0.f, 0.f, 0.f};
    {
      const unsigned short* w2f = P.img + ((size_t)(q * 312 + 52 + wn * 65)) * 512 + lane * 8;
      bf16x8 bA[5], bB[5];
      #pragma unroll
      for (int jn = 0; jn < 5; ++jn) bA[jn] = ld8(w2f + (size_t)(jn * 13 + 0) * 512);
      #pragma unroll
      for (int jn = 0; jn < 5; ++jn) bB[jn] = ld8(w2f + (size_t)(jn * 13 + 1) * 512);
      for (int ks = 0; ks < 13; ks += 2) {
        {
          const bf16x8 a0 = ld8(&h1[(size_t)(wm * 32 + rl) * H1S + ks * 32 + g * 8]);
          const bf16x8 a1 = ld8(&h1[(size_t)(wm * 32 + 16 + rl) * H1S + ks * 32 + g * 8]);
          #pragma unroll
          for (int jn = 0; jn < 5; ++jn) {
            acc2[0][jn] = MFMA(a0, bA[jn], acc2[0][jn]);
            acc2[1][jn] = MFMA(a1, bA[jn], acc2[1][jn]);
          }
          if (ks + 2 < 13) {
            #pragma unroll
            for (int jn = 0; jn < 5; ++jn)
              bA[jn] = ld8(w2f + (size_t)(jn * 13 + ks + 2) * 512);
          }
        }
        if (ks + 1 < 13) {
          const bf16x8 a0 = ld8(&h1[(size_t)(wm * 32 + rl) * H1S + (ks + 1) * 32 + g * 8]);
          const bf16x8 a1 = ld8(&h1[(size_t)(wm * 32 + 16 + rl) * H1S + (ks + 1) * 32 + g * 8]);
          #pragma unroll
          for (int jn = 0; jn < 5; ++jn) {
            acc2[0][jn] = MFMA(a0, bB[jn], acc2[0][jn]);
            acc2[1][jn] = MFMA(a1, bB[jn], acc2[1][jn]);
          }
          if (ks + 3 < 13) {
            #pragma unroll
            for (int jn = 0; jn < 5; ++jn)
              bB[jn] = ld8(w2f + (size_t)(jn * 13 + ks + 3) * 512);
          }
        }
      }
    }

    // ---- epilogue ----
    const float* b2p = q ? P.q2b2 : P.q1b2;
    const float* w3  = q ? P.q2w3 : P.q1w3;
    const float* b3  = q ? P.q2b3 : P.q1b3;
    float xp[2][4];
    #pragma unroll
    for (int mt = 0; mt < 2; ++mt)
      #pragma unroll
      for (int i = 0; i < 4; ++i) xp[mt][i] = 0.f;
    #pragma unroll
    for (int jn = 0; jn < 5; ++jn) {
      const int n = wn * 80 + jn * 16 + rl;
      if (n < 300) {
        const float bv = b2p[n], wv = w3[n];
        #pragma unroll
        for (int mt = 0; mt < 2; ++mt)
          #pragma unroll
          for (int i = 0; i < 4; ++i)
            xp[mt][i] += fmaxf(acc2[mt][jn][i] + bv, 0.f) * wv;
      }
    }
    #pragma unroll
    for (int off = 1; off < 16; off <<= 1)
      #pragma unroll
      for (int mt = 0; mt < 2; ++mt)
        #pragma unroll
        for (int i = 0; i < 4; ++i)
          xp[mt][i] += __shfl_xor(xp[mt][i], off, 64);
    if (rl == 0) {
      #pragma unroll
      for (int mt = 0; mt < 2; ++mt)
        #pragma unroll
        for (int i = 0; i < 4; ++i)
          xred[(wm * 32 + mt * 16 + g * 4 + i) * 4 + wn] = xp[mt][i];
    }
    __syncthreads();                              // xred visible; h1 reads done
    if (tid < ML_ROWS) {
      const float4 xv = *(const float4*)&xred[tid * 4];
      P.out[(size_t)q * BTOT + (size_t)blockIdx.x * ML_ROWS + tid] =
          xv.x + xv.y + xv.z + xv.w + b3[0];
    }
    __syncthreads();                              // xred read done; h1 reusable
  }
}

extern "C" void kernel_launch(void* const* d_in, const int* in_sizes, int n_in,
                              void* d_out, int out_size, void* d_ws, size_t ws_size,
                              hipStream_t stream) {
  (void)in_sizes; (void)n_in; (void)out_size; (void)ws_size;
  P0 A;
  A.state  = (const float*)d_in[0];
  A.action = (const float*)d_in[1];
  A.f1w = (const float*)d_in[2]; A.f1b = (const float*)d_in[3];
  A.f2w = (const float*)d_in[4]; A.f2b = (const float*)d_in[5];
  A.f3w = (const float*)d_in[6]; A.f3b = (const float*)d_in[7];
  A.q1w1 = (const float*)d_in[10]; A.q1b1 = (const float*)d_in[11]; A.q1w2 = (const float*)d_in[12];
  A.q2w1 = (const float*)d_in[16]; A.q2b1 = (const float*)d_in[17]; A.q2w2 = (const float*)d_in[18];
  A.ws  = (unsigned short*)d_ws;
  A.xum = (unsigned short*)((unsigned char*)d_ws + XUM_OFF);
  phase0_kernel<<<dim3(PK_BLK + PH_BLK), dim3(PH_THR), 0, stream>>>(A);

  P1 B;
  B.img  = (const unsigned short*)d_ws;
  B.xum  = (const unsigned short*)((unsigned char*)d_ws + XUM_OFF);
  B.q1b2 = (const float*)d_in[13]; B.q1w3 = (const float*)d_in[14]; B.q1b3 = (const float*)d_in[15];
  B.q2b2 = (const float*)d_in[19]; B.q2w3 = (const float*)d_in[20]; B.q2b3 = (const float*)d_in[21];
  B.out  = (float*)d_out;
  mlp_kernel<<<dim3(ML_BLK), dim3(ML_THR), 0, stream>>>(B);
}

// Round 12
// 104.494 us; speedup vs baseline: 1.5108x; 1.0734x over previous
//
#include <hip/hip_runtime.h>
#include <math.h>

// CriticGraphPolicy, MI355X (gfx950). Round 12.
// R11 post-mortem: latency pipeline + 0 bank conflicts changed nothing ->
// bottleneck is per-CU vector-memory THROUGHPUT: 2.9 MB of fragment loads
// per block (4x w2 redundancy across wm bands, 8x w1). R12: 8 fat waves
// (512 thr): layer2 wave = 64rx80c (5 loads -> 20 MFMAs), layer1 wave =
// 2 row-tiles x col-half (26 frags -> 52 MFMAs). Bytes/block 2.9 -> 1.5 MB,
// ILP 2x. LDS/h1/pipeline/phase0 unchanged from R11.

#define BTOT   65536
#define XUM_OFF 655360ull        // xum offset in d_ws (frag img = 638,976 B)

// phase0 (+fused pack)
#define PK_BLK  78
#define PH_THR  512
#define PH_ROWS 128
#define PH_BLK  (BTOT / PH_ROWS)
#define F1W 0
#define F1B 2112
#define F2W 2176
#define F2B 6272
#define F3W 6336
#define F3B 8384
#define W0_FLOATS 8416

// mlp
#define ML_THR  512              // 8 waves
#define ML_ROWS 128
#define ML_BLK  (BTOT / ML_ROWS)
#define H1S     428              // u16 stride: 856B rows -> 2-way banks

typedef float  f32x4 __attribute__((ext_vector_type(4)));
typedef __bf16 bf16x8 __attribute__((ext_vector_type(8)));
typedef unsigned short u16x8 __attribute__((ext_vector_type(8)));
typedef unsigned short u16x4 __attribute__((ext_vector_type(4)));
typedef unsigned int   u32x2 __attribute__((ext_vector_type(2)));

__device__ __forceinline__ unsigned short f2b(float f) {
  union { float f; unsigned int u; } v; v.f = f;
  return (unsigned short)((v.u + 0x7fffu + ((v.u >> 16) & 1u)) >> 16);
}
__device__ __forceinline__ float b2f(unsigned short u) {
  union { unsigned int u; float f; } v; v.u = ((unsigned int)u) << 16;
  return v.f;
}
__device__ __forceinline__ f32x4 MFMA(bf16x8 a, bf16x8 b, f32x4 c) {
  return __builtin_amdgcn_mfma_f32_16x16x32_bf16(a, b, c, 0, 0, 0);
}
__device__ __forceinline__ bf16x8 ld8(const unsigned short* p) {
  return __builtin_bit_cast(bf16x8, *(const u16x8*)p);
}
__device__ __forceinline__ float ftanh(float x) {
  float e = __builtin_amdgcn_exp2f(x * 2.885390081777927f);
  return (e - 1.0f) * __builtin_amdgcn_rcpf(e + 1.0f);
}

// ---------------- phase0 kernel (+fused fragment pack) -- unchanged R11 -----
struct P0 {
  const float* state; const float* action;
  const float* f1w; const float* f1b;
  const float* f2w; const float* f2b;
  const float* f3w; const float* f3b;
  const float* q1w1; const float* q1b1; const float* q1w2;
  const float* q2w1; const float* q2b1; const float* q2w2;
  unsigned short* ws;
  unsigned short* xum;
};

__global__ __launch_bounds__(PH_THR, 4) void phase0_kernel(P0 P) {
  __shared__ float w0[W0_FLOATS];
  __shared__ unsigned short hx[PH_ROWS * 68];
  const int tid = threadIdx.x;

  if (blockIdx.x < PK_BLK) {          // fragment pack path
    const int gid = blockIdx.x * PH_THR + tid;
    const int lane = gid & 63, f = gid >> 6;
    const int q = f / 312, fl = f - q * 312;
    const float* w1 = q ? P.q2w1 : P.q1w1;
    const float* b1 = q ? P.q2b1 : P.q1b1;
    const float* w2 = q ? P.q2w2 : P.q1w2;
    int nt, ks; const bool isw1 = (fl < 52);
    if (isw1) { nt = fl >> 1; ks = fl & 1; }
    else      { int fl2 = fl - 52; nt = fl2 / 13; ks = fl2 - nt * 13; }
    const int col = nt * 16 + (lane & 15);
    const int k0  = ks * 32 + (lane >> 4) * 8;
    unsigned short v[8];
    #pragma unroll
    for (int j = 0; j < 8; ++j) {
      const int k = k0 + j;
      float x = 0.f;
      if (isw1) {
        if (col < 400) {
          if (k < 39) x = w1[(6 + k) * 400 + col];
          else if (k == 39) x = b1[col];
        }
      } else {
        if (k < 400 && col < 300) x = w2[k * 300 + col];
      }
      v[j] = f2b(x);
    }
    *(u16x8*)(P.ws + (size_t)f * 512 + lane * 8) = *(const u16x8*)v;
    return;
  }

  const int row = tid >> 2, sub = tid & 3, j0 = sub * 16;
  const long grow = (long)(blockIdx.x - PK_BLK) * PH_ROWS + row;

  for (int i = tid; i < 528;  i += PH_THR) *(f32x4*)(w0 + F1W + 4*i) = *(const f32x4*)(P.f1w + 4*i);
  for (int i = tid; i < 16;   i += PH_THR) *(f32x4*)(w0 + F1B + 4*i) = *(const f32x4*)(P.f1b + 4*i);
  for (int i = tid; i < 1024; i += PH_THR) *(f32x4*)(w0 + F2W + 4*i) = *(const f32x4*)(P.f2w + 4*i);
  for (int i = tid; i < 16;   i += PH_THR) *(f32x4*)(w0 + F2B + 4*i) = *(const f32x4*)(P.f2b + 4*i);
  for (int i = tid; i < 512;  i += PH_THR) *(f32x4*)(w0 + F3W + 4*i) = *(const f32x4*)(P.f3w + 4*i);
  for (int i = tid; i < 8;    i += PH_THR) *(f32x4*)(w0 + F3B + 4*i) = *(const f32x4*)(P.f3b + 4*i);

  float sa[33];
  {
    const float4* sp = (const float4*)(P.state + grow * 32);
    #pragma unroll
    for (int c = 0; c < 8; ++c) {
      float4 v = sp[c];
      sa[c*4+0] = v.x; sa[c*4+1] = v.y; sa[c*4+2] = v.z; sa[c*4+3] = v.w;
    }
    sa[32] = P.action[grow];
  }
  __syncthreads();

  float acc[16];
  #pragma unroll
  for (int j = 0; j < 16; ++j) acc[j] = w0[F1B + j0 + j];
  #pragma unroll 4
  for (int i = 0; i < 33; ++i) {
    const float s = sa[i];
    const f32x4* wr = (const f32x4*)&w0[F1W + i * 64 + j0];
    #pragma unroll
    for (int c = 0; c < 4; ++c) {
      f32x4 wv = wr[c];
      acc[c*4+0] += s * wv[0]; acc[c*4+1] += s * wv[1];
      acc[c*4+2] += s * wv[2]; acc[c*4+3] += s * wv[3];
    }
  }
  {
    float ss = 0.f;
    #pragma unroll
    for (int j = 0; j < 16; ++j) ss += acc[j] * acc[j];
    ss += __shfl_xor(ss, 1, 64); ss += __shfl_xor(ss, 2, 64);
    const float sc = 1.f / fmaxf(sqrtf(ss), 1e-12f);
    #pragma unroll
    for (int j = 0; j < 16; ++j) hx[row * 68 + j0 + j] = f2b(ftanh(acc[j] * sc));
  }
  __syncthreads();
  #pragma unroll
  for (int j = 0; j < 16; ++j) acc[j] = w0[F2B + j0 + j];
  #pragma unroll 4
  for (int i0 = 0; i0 < 16; ++i0) {
    const u16x4 hv4 = *(const u16x4*)&hx[row * 68 + i0 * 4];
    #pragma unroll
    for (int u = 0; u < 4; ++u) {
      const float hv = b2f(hv4[u]);
      const f32x4* wr = (const f32x4*)&w0[F2W + (i0 * 4 + u) * 64 + j0];
      #pragma unroll
      for (int c = 0; c < 4; ++c) {
        f32x4 wv = wr[c];
        acc[c*4+0] += hv * wv[0]; acc[c*4+1] += hv * wv[1];
        acc[c*4+2] += hv * wv[2]; acc[c*4+3] += hv * wv[3];
      }
    }
  }
  __syncthreads();
  #pragma unroll
  for (int j = 0; j < 16; ++j) hx[row * 68 + j0 + j] = f2b(ftanh(acc[j]));
  __syncthreads();
  const int j0m = sub * 8;
  float am[8];
  #pragma unroll
  for (int j = 0; j < 8; ++j) am[j] = w0[F3B + j0m + j];
  #pragma unroll 4
  for (int i0 = 0; i0 < 16; ++i0) {
    const u16x4 hv4 = *(const u16x4*)&hx[row * 68 + i0 * 4];
    #pragma unroll
    for (int u = 0; u < 4; ++u) {
      const float hv = b2f(hv4[u]);
      const f32x4* wr = (const f32x4*)&w0[F3W + (i0 * 4 + u) * 32 + j0m];
      #pragma unroll
      for (int c = 0; c < 2; ++c) {
        f32x4 wv = wr[c];
        am[c*4+0] += hv * wv[0]; am[c*4+1] += hv * wv[1];
        am[c*4+2] += hv * wv[2]; am[c*4+3] += hv * wv[3];
      }
    }
  }
  float sm = 0.f;
  #pragma unroll
  for (int j = 0; j < 8; ++j) sm += am[j] * am[j];
  sm += __shfl_xor(sm, 1, 64); sm += __shfl_xor(sm, 2, 64);
  const float scm = 1.f / fmaxf(sqrtf(sm), 1e-12f);
  __syncthreads();
  #pragma unroll
  for (int j = 0; j < 8; ++j) hx[row * 68 + j0m + j] = f2b(am[j] * scm);
  __syncthreads();
  {
    u16x8 v0, v1;
    #pragma unroll
    for (int t = 0; t < 16; ++t) {
      const int c = j0 + t;
      unsigned short u;
      if      (c < 3)  u = f2b(sa[c]);
      else if (c < 6)  u = f2b(sa[c - 3]);
      else if (c < 38) u = hx[row * 68 + (c - 6)];
      else if (c == 38) u = f2b(sa[32]);
      else if (c == 39) u = 0x3f80;
      else              u = 0;
      if (t < 8) v0[t] = u; else v1[t - 8] = u;
    }
    unsigned short* dst = P.xum + (size_t)grow * 64 + j0;
    *(u16x8*)dst = v0;
    *(u16x8*)(dst + 8) = v1;
  }
}

// ---------------- mlp kernel: 8 fat waves ----------------
struct P1 {
  const unsigned short* img; const unsigned short* xum;
  const float* q1b2; const float* q1w3; const float* q1b3;
  const float* q2b2; const float* q2w3; const float* q2b3;
  float* out;
};

__global__ __launch_bounds__(ML_THR, 2) void mlp_kernel(P1 P) {
  __shared__ __align__(16) unsigned short h1[ML_ROWS * H1S]; // 109,568 B
  __shared__ float xred[ML_ROWS * 4];

  const int tid  = threadIdx.x;
  const int lane = tid & 63, w = tid >> 6;        // 8 waves
  const int rl = lane & 15, g = lane >> 4;

  // layer1: wave -> row-tile pair rp (32 rows) x col-half ch (13 nt per q)
  const int rp = w & 3, ch = w >> 2;
  // layer2: wave -> 64-row band wm (4 mt) x 80-col quarter wn (5 jn)
  const int wm = w >> 2, wn = w & 3;

  // xum A-fragments for the 2 row-tiles
  const unsigned short* xr0 = P.xum + ((size_t)blockIdx.x * ML_ROWS + rp * 32 + rl) * 64;
  const bf16x8 af0k0 = ld8(xr0 + g * 8);
  const bf16x8 af0k1 = ld8(xr0 + 32 + g * 8);
  const unsigned short* xr1 = xr0 + 16 * 64;
  const bf16x8 af1k0 = ld8(xr1 + g * 8);
  const bf16x8 af1k1 = ld8(xr1 + 32 + g * 8);

  for (int q = 0; q < 2; ++q) {
    // ---- layer1 (swapped operands): 13 nt x 2 row-tiles, depth-2 pipeline --
    {
      const unsigned short* w1f = P.img + ((size_t)(q * 312 + ch * 26)) * 512 + lane * 8;
      unsigned short* h1w0 = &h1[(size_t)(rp * 32 + rl) * H1S + ch * 208 + g * 4];
      unsigned short* h1w1 = &h1[(size_t)(rp * 32 + 16 + rl) * H1S + ch * 208 + g * 4];
      bf16x8 wA0 = ld8(w1f + 0 * 512), wA1 = ld8(w1f + 1 * 512);
      bf16x8 wB0 = ld8(w1f + 2 * 512), wB1 = ld8(w1f + 3 * 512);
      for (int t = 0; t < 13; t += 2) {
        {
          f32x4 a = (f32x4){0.f, 0.f, 0.f, 0.f};
          f32x4 b = (f32x4){0.f, 0.f, 0.f, 0.f};
          a = MFMA(wA0, af0k0, a); a = MFMA(wA1, af0k1, a);
          b = MFMA(wA0, af1k0, b); b = MFMA(wA1, af1k1, b);
          if (t + 2 < 13) {
            wA0 = ld8(w1f + (size_t)((t + 2) * 2) * 512);
            wA1 = ld8(w1f + (size_t)((t + 2) * 2 + 1) * 512);
          }
          unsigned int p01, p23, q01, q23;
          const float a0 = fmaxf(a[0], 0.f), a1 = fmaxf(a[1], 0.f);
          const float a2 = fmaxf(a[2], 0.f), a3 = fmaxf(a[3], 0.f);
          const float b0 = fmaxf(b[0], 0.f), b1 = fmaxf(b[1], 0.f);
          const float b2 = fmaxf(b[2], 0.f), b3 = fmaxf(b[3], 0.f);
          asm("v_cvt_pk_bf16_f32 %0, %1, %2" : "=v"(p01) : "v"(a0), "v"(a1));
          asm("v_cvt_pk_bf16_f32 %0, %1, %2" : "=v"(p23) : "v"(a2), "v"(a3));
          asm("v_cvt_pk_bf16_f32 %0, %1, %2" : "=v"(q01) : "v"(b0), "v"(b1));
          asm("v_cvt_pk_bf16_f32 %0, %1, %2" : "=v"(q23) : "v"(b2), "v"(b3));
          u32x2 pk; pk[0] = p01; pk[1] = p23;
          u32x2 qk; qk[0] = q01; qk[1] = q23;
          *(u32x2*)(h1w0 + t * 16) = pk;
          *(u32x2*)(h1w1 + t * 16) = qk;
        }
        if (t + 1 < 13) {
          f32x4 a = (f32x4){0.f, 0.f, 0.f, 0.f};
          f32x4 b = (f32x4){0.f, 0.f, 0.f, 0.f};
          a = MFMA(wB0, af0k0, a); a = MFMA(wB1, af0k1, a);
          b = MFMA(wB0, af1k0, b); b = MFMA(wB1, af1k1, b);
          if (t + 3 < 13) {
            wB0 = ld8(w1f + (size_t)((t + 3) * 2) * 512);
            wB1 = ld8(w1f + (size_t)((t + 3) * 2 + 1) * 512);
          }
          unsigned int p01, p23, q01, q23;
          const float a0 = fmaxf(a[0], 0.f), a1 = fmaxf(a[1], 0.f);
          const float a2 = fmaxf(a[2], 0.f), a3 = fmaxf(a[3], 0.f);
          const float b0 = fmaxf(b[0], 0.f), b1 = fmaxf(b[1], 0.f);
          const float b2 = fmaxf(b[2], 0.f), b3 = fmaxf(b[3], 0.f);
          asm("v_cvt_pk_bf16_f32 %0, %1, %2" : "=v"(p01) : "v"(a0), "v"(a1));
          asm("v_cvt_pk_bf16_f32 %0, %1, %2" : "=v"(p23) : "v"(a2), "v"(a3));
          asm("v_cvt_pk_bf16_f32 %0, %1, %2" : "=v"(q01) : "v"(b0), "v"(b1));
          asm("v_cvt_pk_bf16_f32 %0, %1, %2" : "=v"(q23) : "v"(b2), "v"(b3));
          u32x2 pk; pk[0] = p01; pk[1] = p23;
          u32x2 qk; qk[0] = q01; qk[1] = q23;
          *(u32x2*)(h1w0 + (t + 1) * 16) = pk;
          *(u32x2*)(h1w1 + (t + 1) * 16) = qk;
        }
      }
    }
    __syncthreads();                              // h1 complete

    // ---- layer2: 4 mt x 5 jn x 13 ks; depth-2 pipelined B-frags ----
    f32x4 acc2[4][5];
    #pragma unroll
    for (int mt = 0; mt < 4; ++mt)
      #pragma unroll
      for (int jn = 0; jn < 5; ++jn) acc2[mt][jn] = (f32x4){0.f, 0.f, 0.f, 0.f};
    {
      const unsigned short* w2f = P.img + ((size_t)(q * 312 + 52 + wn * 65)) * 512 + lane * 8;
      bf16x8 bA[5], bB[5];
      #pragma unroll
      for (int jn = 0; jn < 5; ++jn) bA[jn] = ld8(w2f + (size_t)(jn * 13 + 0) * 512);
      #pragma unroll
      for (int jn = 0; jn < 5; ++jn) bB[jn] = ld8(w2f + (size_t)(jn * 13 + 1) * 512);
      for (int ks = 0; ks < 13; ks += 2) {
        {
          bf16x8 am[4];
          #pragma unroll
          for (int mt = 0; mt < 4; ++mt)
            am[mt] = ld8(&h1[(size_t)(wm * 64 + mt * 16 + rl) * H1S + ks * 32 + g * 8]);
          #pragma unroll
          for (int jn = 0; jn < 5; ++jn)
            #pragma unroll
            for (int mt = 0; mt < 4; ++mt)
              acc2[mt][jn] = MFMA(am[mt], bA[jn], acc2[mt][jn]);
          if (ks + 2 < 13) {
            #pragma unroll
            for (int jn = 0; jn < 5; ++jn)
              bA[jn] = ld8(w2f + (size_t)(jn * 13 + ks + 2) * 512);
          }
        }
        if (ks + 1 < 13) {
          bf16x8 am[4];
          #pragma unroll
          for (int mt = 0; mt < 4; ++mt)
            am[mt] = ld8(&h1[(size_t)(wm * 64 + mt * 16 + rl) * H1S + (ks + 1) * 32 + g * 8]);
          #pragma unroll
          for (int jn = 0; jn < 5; ++jn)
            #pragma unroll
            for (int mt = 0; mt < 4; ++mt)
              acc2[mt][jn] = MFMA(am[mt], bB[jn], acc2[mt][jn]);
          if (ks + 3 < 13) {
            #pragma unroll
            for (int jn = 0; jn < 5; ++jn)
              bB[jn] = ld8(w2f + (size_t)(jn * 13 + ks + 3) * 512);
          }
        }
      }
    }

    // ---- epilogue ----
    const float* b2p = q ? P.q2b2 : P.q1b2;
    const float* w3  = q ? P.q2w3 : P.q1w3;
    const float* b3  = q ? P.q2b3 : P.q1b3;
    float xp[4][4];
    #pragma unroll
    for (int mt = 0; mt < 4; ++mt)
      #pragma unroll
      for (int i = 0; i < 4; ++i) xp[mt][i] = 0.f;
    #pragma unroll
    for (int jn = 0; jn < 5; ++jn) {
      const int n = wn * 80 + jn * 16 + rl;
      if (n < 300) {
        const float bv = b2p[n], wv = w3[n];
        #pragma unroll
        for (int mt = 0; mt < 4; ++mt)
          #pragma unroll
          for (int i = 0; i < 4; ++i)
            xp[mt][i] += fmaxf(acc2[mt][jn][i] + bv, 0.f) * wv;
      }
    }
    #pragma unroll
    for (int off = 1; off < 16; off <<= 1)
      #pragma unroll
      for (int mt = 0; mt < 4; ++mt)
        #pragma unroll
        for (int i = 0; i < 4; ++i)
          xp[mt][i] += __shfl_xor(xp[mt][i], off, 64);
    if (rl == 0) {
      #pragma unroll
      for (int mt = 0; mt < 4; ++mt)
        #pragma unroll
        for (int i = 0; i < 4; ++i)
          xred[(wm * 64 + mt * 16 + g * 4 + i) * 4 + wn] = xp[mt][i];
    }
    __syncthreads();                              // xred visible; h1 reads done
    if (tid < ML_ROWS) {
      const float4 xv = *(const float4*)&xred[tid * 4];
      P.out[(size_t)q * BTOT + (size_t)blockIdx.x * ML_ROWS + tid] =
          xv.x + xv.y + xv.z + xv.w + b3[0];
    }
    __syncthreads();                              // xred read done; h1 reusable
  }
}

extern "C" void kernel_launch(void* const* d_in, const int* in_sizes, int n_in,
                              void* d_out, int out_size, void* d_ws, size_t ws_size,
                              hipStream_t stream) {
  (void)in_sizes; (void)n_in; (void)out_size; (void)ws_size;
  P0 A;
  A.state  = (const float*)d_in[0];
  A.action = (const float*)d_in[1];
  A.f1w = (const float*)d_in[2]; A.f1b = (const float*)d_in[3];
  A.f2w = (const float*)d_in[4]; A.f2b = (const float*)d_in[5];
  A.f3w = (const float*)d_in[6]; A.f3b = (const float*)d_in[7];
  A.q1w1 = (const float*)d_in[10]; A.q1b1 = (const float*)d_in[11]; A.q1w2 = (const float*)d_in[12];
  A.q2w1 = (const float*)d_in[16]; A.q2b1 = (const float*)d_in[17]; A.q2w2 = (const float*)d_in[18];
  A.ws  = (unsigned short*)d_ws;
  A.xum = (unsigned short*)((unsigned char*)d_ws + XUM_OFF);
  phase0_kernel<<<dim3(PK_BLK + PH_BLK), dim3(PH_THR), 0, stream>>>(A);

  P1 B;
  B.img  = (const unsigned short*)d_ws;
  B.xum  = (const unsigned short*)((unsigned char*)d_ws + XUM_OFF);
  B.q1b2 = (const float*)d_in[13]; B.q1w3 = (const float*)d_in[14]; B.q1b3 = (const float*)d_in[15];
  B.q2b2 = (const float*)d_in[19]; B.q2w3 = (const float*)d_in[20]; B.q2b3 = (const float*)d_in[21];
  B.out  = (float*)d_out;
  mlp_kernel<<<dim3(ML_BLK), dim3(ML_THR), 0, stream>>>(B);
}